// Round 18
// baseline (71.270 us; speedup 1.0000x reference)
//
#include <hip/hip_runtime.h>
#include <hip/hip_bf16.h>
#include <stdint.h>

#define B_ 4
#define K_ 2048
#define D_ 512
#define H_ 8
#define ATTN_ 128
#define M_ (B_ * K_)   // 8192

typedef __attribute__((ext_vector_type(4))) float f32x4;
typedef __attribute__((ext_vector_type(8))) short bf16x8;
typedef __attribute__((ext_vector_type(8))) unsigned short u16x8;
typedef __attribute__((ext_vector_type(2))) unsigned int u32x2;
typedef __attribute__((ext_vector_type(4))) unsigned int u32x4;

__device__ __forceinline__ unsigned short f2bf(float f) {
    union { float f; unsigned int i; } x; x.f = f;
    unsigned int r = x.i + 0x7fffu + ((x.i >> 16) & 1u);   // RNE
    return (unsigned short)(r >> 16);
}
__device__ __forceinline__ float bf2f(unsigned short u) {
    union { unsigned int i; float f; } x; x.i = ((unsigned int)u) << 16; return x.f;
}
__device__ __forceinline__ void gload_lds16(const unsigned short* g, unsigned short* l) {
    __builtin_amdgcn_global_load_lds(
        (const __attribute__((address_space(1))) void*)g,
        (__attribute__((address_space(3))) void*)l, 16, 0, 0);
}
__device__ __forceinline__ unsigned lds_addr(const void* p) {
    return (unsigned)(unsigned long long)
        (const __attribute__((address_space(3))) void*)p;
}

// ---------------------------------------------------------------------------
// fp32 -> bf16 conversion: query/key/value + 4 weights (7 tensors, 1 launch)
// ---------------------------------------------------------------------------
struct Cvt { const float* s; unsigned short* d; int n8; };
struct CvtA { Cvt c[7]; };

__global__ __launch_bounds__(256)
void cvt_multi(CvtA a) {
    const Cvt c = a.c[blockIdx.y];
    const float4* s4 = (const float4*)c.s;
    u16x8* d8 = (u16x8*)c.d;
    for (int g = blockIdx.x * 256 + threadIdx.x; g < c.n8; g += gridDim.x * 256) {
        float4 f0 = s4[2 * g], f1 = s4[2 * g + 1];
        u16x8 o;
        o[0] = f2bf(f0.x); o[1] = f2bf(f0.y); o[2] = f2bf(f0.z); o[3] = f2bf(f0.w);
        o[4] = f2bf(f1.x); o[5] = f2bf(f1.y); o[6] = f2bf(f1.z); o[7] = f2bf(f1.w);
        d8[g] = o;
    }
}

// ---------------------------------------------------------------------------
// Generic 64x128-tile bf16 GEMM (r17-validated gemm_o64 structure, ~614 TF):
//   C[8192,512] = A[8192,512] @ W[512,512]^T + bias.
//   BK=64, 256 thr (4 waves 2x2, wave tile 32x64), As[2]+Bs[2] = 48 KB
//   -> 3 blocks/CU; all-gload_lds staging issued BEFORE compute; ONE
//   barrier per K-step (the structural win over r16's reg-staged QKV).
// 2-job batching: 512 blocks per z; z = swizzled-id >> 9.
// ---------------------------------------------------------------------------
struct G2 {
    const unsigned short* A[2];
    const unsigned short* Wt[2];
    const float* bias[2];
    void* C[2];
};

template<bool OUT_BF16>
__global__ __launch_bounds__(256, 3)
void gemm64b(G2 args)
{
    __shared__ unsigned short As[2][64 * 64];    // 8 KB x2
    __shared__ unsigned short Bs[2][128 * 64];   // 16 KB x2

    const int id = blockIdx.x;
    const int lg = (id & 7) * (gridDim.x >> 3) + (id >> 3);  // XCD-contiguous
    const int z  = lg >> 9;                      // 512 blocks per z
    const int r5 = lg & 511;
    const int mt = r5 >> 2;
    const int nt = r5 & 3;
    const int bm = mt * 64;
    const int bn = nt * 128;

    const unsigned short* A = args.A[z];
    const unsigned short* W = args.Wt[z];
    const float* bias = args.bias[z];
    void* C = args.C[z];

    const int tid = threadIdx.x;
    const int w   = tid >> 6;                    // wave 0..3
    const int l   = tid & 63;
    const int lr  = l & 15;
    const int lhi = l >> 4;
    const int wm  = (w >> 1) * 32;               // 2x2 wave grid, 32x64/wave
    const int wn  = (w & 1) * 64;

    f32x4 acc[2][4];
    #pragma unroll
    for (int m = 0; m < 2; ++m)
        #pragma unroll
        for (int n = 0; n < 4; ++n) acc[m][n] = (f32x4){0.f, 0.f, 0.f, 0.f};

    auto stage = [&](int buf, int t) {
        // A: 64 rows x 8 chunks = 512 chunks, 8 groups (2/wave)
        #pragma unroll
        for (int it = 0; it < 2; ++it) {
            const int cg  = it * 4 + w;
            const int cid = cg * 64 + l;
            const int r = cid >> 3;
            const int c = (cid & 7) ^ (r & 7);
            gload_lds16(A + (size_t)(bm + r) * D_ + t * 64 + c * 8,
                        &As[buf][cg * 512]);
        }
        // B: 128 rows x 8 chunks = 1024 chunks, 16 groups (4/wave)
        #pragma unroll
        for (int it = 0; it < 4; ++it) {
            const int cg  = it * 4 + w;
            const int cid = cg * 64 + l;
            const int r = cid >> 3;
            const int c = (cid & 7) ^ (r & 7);
            gload_lds16(W + (size_t)(bn + r) * D_ + t * 64 + c * 8,
                        &Bs[buf][cg * 512]);
        }
    };

    stage(0, 0);
    __syncthreads();

    int buf = 0;
    for (int t = 0; t < 8; ++t) {
        if (t < 7) stage(buf ^ 1, t + 1);        // issue BEFORE compute
        __builtin_amdgcn_s_setprio(1);
        #pragma unroll
        for (int kk = 0; kk < 2; ++kk) {
            bf16x8 af[2], bfr[4];
            #pragma unroll
            for (int fm = 0; fm < 2; ++fm) {
                const int row = wm + fm * 16 + lr;
                const int sl  = (kk * 4 + lhi) ^ (row & 7);
                af[fm] = *(const bf16x8*)&As[buf][row * 64 + sl * 8];
            }
            #pragma unroll
            for (int fn = 0; fn < 4; ++fn) {
                const int row = wn + fn * 16 + lr;
                const int sl  = (kk * 4 + lhi) ^ (row & 7);
                bfr[fn] = *(const bf16x8*)&Bs[buf][row * 64 + sl * 8];
            }
            #pragma unroll
            for (int fm = 0; fm < 2; ++fm)
                #pragma unroll
                for (int fn = 0; fn < 4; ++fn)
                    acc[fm][fn] = __builtin_amdgcn_mfma_f32_16x16x32_bf16(
                        af[fm], bfr[fn], acc[fm][fn], 0, 0, 0);
        }
        __builtin_amdgcn_s_setprio(0);
        __syncthreads();                         // loads had full compute to land
        buf ^= 1;
    }

    float bv[4];
    #pragma unroll
    for (int fn = 0; fn < 4; ++fn) bv[fn] = bias[bn + wn + fn * 16 + lr];

    #pragma unroll
    for (int fm = 0; fm < 2; ++fm)
        #pragma unroll
        for (int fn = 0; fn < 4; ++fn)
            #pragma unroll
            for (int rr = 0; rr < 4; ++rr) {
                const int row = bm + wm + fm * 16 + lhi * 4 + rr;
                const int col = bn + wn + fn * 16 + lr;
                const float val = acc[fm][fn][rr] + bv[fn];
                if (OUT_BF16)
                    ((unsigned short*)C)[(size_t)row * 512 + col] = f2bf(val);
                else
                    ((float*)C)[(size_t)row * 512 + col] = val;
            }
}

// ---------------------------------------------------------------------------
// MFMA banded-causal local attention (r17-validated: P unioned into Ksh,
// 49.2 KB -> 3 blocks/CU). Unchanged.
// ---------------------------------------------------------------------------
__global__ __launch_bounds__(256, 3)
void attn_mfma(const unsigned short* __restrict__ qb,
               const unsigned short* __restrict__ kb,
               const unsigned short* __restrict__ vb,
               unsigned short* __restrict__ ob)
{
    __shared__ unsigned short Ksh[192 * 64];      // 24 KB; becomes P after QK^T
    __shared__ unsigned short Vsh[4 * 192 * 16];  // 24 KB

    const int flat = blockIdx.x + 32 * (blockIdx.y + 8 * blockIdx.z);
    const int lg   = (flat & 7) * 128 + (flat >> 3);
    const int tile = lg & 31;
    const int h    = (lg >> 5) & 7;
    const int b    = lg >> 8;

    const int i0 = tile * 64;
    const int j0 = i0 - 128;
    const int tid = threadIdx.x;
    const int w   = tid >> 6;
    const int l   = tid & 63;
    const int lr  = l & 15;
    const int lhi = l >> 4;
    const float scale = 0.0220970869120796f;

    const size_t hbase = ((size_t)b * K_) * 512 + (size_t)h * 64;
    const unsigned short* kh = kb + hbase;
    const unsigned short* vh = vb + hbase;
    const unsigned short* qh = qb + hbase;
    unsigned short* oh = ob + hbase;

    #pragma unroll
    for (int it = 0; it < 6; ++it) {
        const int cg  = it * 4 + w;
        const int cid = cg * 64 + l;
        const int r = cid >> 3, c = cid & 7;
        const int cs = c ^ (r & 7);
        int j = j0 + r; if (j < 0) j = 0;
        gload_lds16(kh + (size_t)j * 512 + cs * 8, &Ksh[cg * 64 * 8]);
    }
    #pragma unroll
    for (int it = 0; it < 6; ++it) {
        const int cg  = it * 4 + w;
        const int cid = cg * 64 + l;
        const int blk = cid / 384;
        const int rem = cid - blk * 384;
        const int prow = rem >> 1, hf = rem & 1;
        const int a = prow >> 2, bb = prow & 3;
        const int k = (a < 24) ? (8 * a + bb) : (8 * (a - 24) + 4 + bb);
        int j = j0 + k; if (j < 0) j = 0;
        gload_lds16(vh + (size_t)j * 512 + blk * 16 + hf * 8, &Vsh[cg * 64 * 8]);
    }

    bf16x8 qa[2];
    {
        const unsigned short* qrow = qh + (size_t)(i0 + 16 * w + lr) * 512;
        qa[0] = *(const bf16x8*)(qrow + lhi * 8);
        qa[1] = *(const bf16x8*)(qrow + 32 + lhi * 8);
    }
    __syncthreads();

    const int jcbase = w & ~1;
    f32x4 sacc[10];
    #pragma unroll
    for (int jc = 0; jc < 10; ++jc) sacc[jc] = (f32x4){0.f, 0.f, 0.f, 0.f};

    __builtin_amdgcn_s_setprio(1);
    #pragma unroll
    for (int kk = 0; kk < 2; ++kk) {
        const int ch = (kk * 4 + lhi) ^ (lr & 7);
        #pragma unroll
        for (int jc = 0; jc < 10; ++jc) {
            const int row = (jcbase + jc) * 16 + lr;
            bf16x8 kf = *(const bf16x8*)&Ksh[row * 64 + ch * 8];
            sacc[jc] = __builtin_amdgcn_mfma_f32_16x16x32_bf16(
                qa[kk], kf, sacc[jc], 0, 0, 0);
        }
    }
    __builtin_amdgcn_s_setprio(0);

    __syncthreads();   // ALL waves done reading K -> Ksh reusable as P

    unsigned short* myP = &Ksh[w * 16 * 168];
    const int lo0 = 128 - i0;
    float lsum[4] = {0.f, 0.f, 0.f, 0.f};
    #pragma unroll
    for (int jc = 0; jc < 10; ++jc) {
        const int jcol = (jcbase + jc) * 16 + lr;
        #pragma unroll
        for (int rr = 0; rr < 4; ++rr) {
            const int iloc = 16 * w + 4 * lhi + rr;
            const bool ok = (jcol >= iloc) && (jcol <= iloc + ATTN_) && (jcol >= lo0);
            const float p = ok ? __expf(fminf(sacc[jc][rr] * scale, 80.f)) : 0.f;
            lsum[rr] += p;
            myP[(4 * lhi + rr) * 168 + jc * 16 + lr] = f2bf(p);
        }
    }
    #pragma unroll
    for (int rr = 0; rr < 4; ++rr) {
        float s = lsum[rr];
        s += __shfl_xor(s, 1, 16);
        s += __shfl_xor(s, 2, 16);
        s += __shfl_xor(s, 4, 16);
        s += __shfl_xor(s, 8, 16);
        lsum[rr] = s;
    }

    const int kcbase = w >> 1;
    f32x4 oacc[4];
    #pragma unroll
    for (int fn = 0; fn < 4; ++fn) oacc[fn] = (f32x4){0.f, 0.f, 0.f, 0.f};
    const unsigned vbase = lds_addr(&Vsh[0]) + (unsigned)(l * 8);

    for (int kc5 = 0; kc5 < 5; ++kc5) {
        const int kc = kcbase + kc5;
        bf16x8 pa = *(const bf16x8*)&myP[lr * 168 + kc5 * 32 + lhi * 8];
        u32x2 vlo[4], vhi[4];
        #pragma unroll
        for (int fn = 0; fn < 4; ++fn) {
            const unsigned addr = vbase + (unsigned)((fn * 3072 + kc * 256) * 2);
            asm volatile("ds_read_b64_tr_b16 %0, %1" : "=v"(vlo[fn]) : "v"(addr));
            asm volatile("ds_read_b64_tr_b16 %0, %1 offset:3072"
                         : "=v"(vhi[fn]) : "v"(addr));
        }
        asm volatile("s_waitcnt lgkmcnt(0)" ::: "memory");
        __builtin_amdgcn_sched_barrier(0);
        __builtin_amdgcn_s_setprio(1);
        #pragma unroll
        for (int fn = 0; fn < 4; ++fn) {
            union { u32x2 h[2]; bf16x8 v; } u;
            u.h[0] = vlo[fn]; u.h[1] = vhi[fn];
            oacc[fn] = __builtin_amdgcn_mfma_f32_16x16x32_bf16(
                pa, u.v, oacc[fn], 0, 0, 0);
        }
        __builtin_amdgcn_s_setprio(0);
    }

    float inv[4];
    #pragma unroll
    for (int rr = 0; rr < 4; ++rr) inv[rr] = 1.f / lsum[rr];
    #pragma unroll
    for (int fn = 0; fn < 4; ++fn)
        #pragma unroll
        for (int rr = 0; rr < 4; ++rr) {
            const int row = i0 + 16 * w + 4 * lhi + rr;
            oh[(size_t)row * 512 + fn * 16 + lr] = f2bf(oacc[fn][rr] * inv[rr]);
        }
}

// ---------------------------------------------------------------------------
extern "C" void kernel_launch(void* const* d_in, const int* in_sizes, int n_in,
                              void* d_out, int out_size, void* d_ws, size_t ws_size,
                              hipStream_t stream)
{
    const float* query = (const float*)d_in[0];
    const float* key   = (const float*)d_in[1];
    const float* value = (const float*)d_in[2];
    const float* W_q   = (const float*)d_in[3];
    const float* b_q   = (const float*)d_in[4];
    const float* W_k   = (const float*)d_in[5];
    const float* b_k   = (const float*)d_in[6];
    const float* W_v   = (const float*)d_in[7];
    const float* b_v   = (const float*)d_in[8];
    const float* W_o   = (const float*)d_in[9];
    const float* b_o   = (const float*)d_in[10];
    float* out = (float*)d_out;

    // bf16 workspace, 44 MB peak (< 50.3 MB proven):
    const size_t NX = (size_t)M_ * 512;          // 4,194,304 shorts
    const size_t NW = 512 * 512;
    unsigned short* xq  = (unsigned short*)d_ws;
    unsigned short* xk  = xq + NX;
    unsigned short* xv  = xk + NX;
    unsigned short* wqb = xv + NX;
    unsigned short* wkb = wqb + NW;
    unsigned short* wvb = wkb + NW;
    unsigned short* wob = wvb + NW;
    unsigned short* qp  = wob + NW;
    unsigned short* kp  = qp + NX;
    unsigned short* vp  = xq;   // aliases xq (dead after Q-GEMM; stream-ordered)
    unsigned short* ap  = xk;   // aliases xk (dead after K-GEMM; stream-ordered)

    const int NX8 = (int)(NX / 8), NW8 = (int)(NW / 8);

    CvtA a;
    a.c[0] = { query, xq,  NX8 };
    a.c[1] = { key,   xk,  NX8 };
    a.c[2] = { value, xv,  NX8 };
    a.c[3] = { W_q,   wqb, NW8 };
    a.c[4] = { W_k,   wkb, NW8 };
    a.c[5] = { W_v,   wvb, NW8 };
    a.c[6] = { W_o,   wob, NW8 };
    cvt_multi<<<dim3(512, 7), 256, 0, stream>>>(a);

    // Q + K projections fused (1024 blocks, z = lg>>9)
    G2 gqk;
    gqk.A[0] = xq;  gqk.A[1] = xk;
    gqk.Wt[0] = wqb; gqk.Wt[1] = wkb;
    gqk.bias[0] = b_q; gqk.bias[1] = b_k;
    gqk.C[0] = qp; gqk.C[1] = kp;
    gemm64b<true><<<1024, 256, 0, stream>>>(gqk);

    // V projection (512 blocks; vp aliases xq — safe after Q-GEMM read xq)
    G2 gv;
    gv.A[0] = gv.A[1] = xv;
    gv.Wt[0] = gv.Wt[1] = wvb;
    gv.bias[0] = gv.bias[1] = b_v;
    gv.C[0] = gv.C[1] = vp;
    gemm64b<true><<<512, 256, 0, stream>>>(gv);

    attn_mfma<<<dim3(32, 8, 4), 256, 0, stream>>>(qp, kp, vp, ap);

    // Output projection (512 blocks, fp32 out)
    G2 go;
    go.A[0] = go.A[1] = ap;
    go.Wt[0] = go.Wt[1] = wob;
    go.bias[0] = go.bias[1] = b_o;
    go.C[0] = go.C[1] = out;
    gemm64b<false><<<512, 256, 0, stream>>>(go);
}

// Round 19
// 56.763 us; speedup vs baseline: 1.2556x; 1.2556x over previous
//
#include <hip/hip_runtime.h>
#include <hip/hip_bf16.h>
#include <stdint.h>

#define B_ 4
#define K_ 2048
#define D_ 512
#define H_ 8
#define ATTN_ 128
#define M_ (B_ * K_)   // 8192

typedef __attribute__((ext_vector_type(4))) float f32x4;
typedef __attribute__((ext_vector_type(8))) short bf16x8;
typedef __attribute__((ext_vector_type(8))) unsigned short u16x8;
typedef __attribute__((ext_vector_type(2))) unsigned int u32x2;
typedef __attribute__((ext_vector_type(4))) unsigned int u32x4;

__device__ __forceinline__ unsigned short f2bf(float f) {
    union { float f; unsigned int i; } x; x.f = f;
    unsigned int r = x.i + 0x7fffu + ((x.i >> 16) & 1u);   // RNE
    return (unsigned short)(r >> 16);
}
__device__ __forceinline__ float bf2f(unsigned short u) {
    union { unsigned int i; float f; } x; x.i = ((unsigned int)u) << 16; return x.f;
}
__device__ __forceinline__ unsigned cvtpk(float lo, float hi) {   // r11/r16-validated
    unsigned r;
    asm("v_cvt_pk_bf16_f32 %0, %1, %2" : "=v"(r) : "v"(lo), "v"(hi));
    return r;
}
__device__ __forceinline__ void gload_lds16(const unsigned short* g, unsigned short* l) {
    __builtin_amdgcn_global_load_lds(
        (const __attribute__((address_space(1))) void*)g,
        (__attribute__((address_space(3))) void*)l, 16, 0, 0);
}
__device__ __forceinline__ unsigned lds_addr(const void* p) {
    return (unsigned)(unsigned long long)
        (const __attribute__((address_space(3))) void*)p;
}

// ---------------------------------------------------------------------------
// fp32 -> bf16 conversion: weights only (4 tensors) — r17 verbatim
// ---------------------------------------------------------------------------
struct Cvt { const float* s; unsigned short* d; int n8; };
struct CvtA { Cvt c[4]; };

__global__ __launch_bounds__(256)
void cvt_multi(CvtA a) {
    const Cvt c = a.c[blockIdx.y];
    const float4* s4 = (const float4*)c.s;
    u16x8* d8 = (u16x8*)c.d;
    for (int g = blockIdx.x * 256 + threadIdx.x; g < c.n8; g += gridDim.x * 256) {
        float4 f0 = s4[2 * g], f1 = s4[2 * g + 1];
        u16x8 o;
        o[0] = f2bf(f0.x); o[1] = f2bf(f0.y); o[2] = f2bf(f0.z); o[3] = f2bf(f0.w);
        o[4] = f2bf(f1.x); o[5] = f2bf(f1.y); o[6] = f2bf(f1.z); o[7] = f2bf(f1.w);
        d8[g] = o;
    }
}

// ---------------------------------------------------------------------------
// QKV GEMM — 64x128 tile, FULL double-buffer at 48 KB, ONE barrier/step.
// r15's full-dbuf failed only via 64 KB -> 1 block/CU; at 64-row A the same
// schedule fits 48 KB -> 3 blocks/CU (r17-proven occupancy point).
// Per step t: loadA(t+1)->reg (2 float4/thr) + stageB(t+1)->Bs[buf^1]
// BEFORE compute; 32 MFMA/wave on buffers[buf]; writeA->As[buf^1] (its
// readers finished at the t-1 barrier; fa's vmcnt wait had full compute
// cover); ONE __syncthreads (B gloads full-phase old + A ds_writes).
// Wave math = r17 o64 (2x2 waves, 32x64/wave); A-path = r17 QKV cvt_pk.
// ---------------------------------------------------------------------------
struct GArgs {
    const void* A[3];
    const unsigned short* Wt[3];
    const float* bias[3];
    void* C[3];
};

__global__ __launch_bounds__(256, 3)
void gemm_qkv64(GArgs args)
{
    __shared__ unsigned short As[2][64 * 64];    // 8 KB x2
    __shared__ unsigned short Bs[2][128 * 64];   // 16 KB x2

    const int id = blockIdx.x;                   // 1536 = 3z x 128mt x 4nt
    const int lg = (id & 7) * (gridDim.x >> 3) + (id >> 3);  // XCD-contiguous
    const int z  = lg >> 9;
    const int r5 = lg & 511;
    const int mt = r5 >> 2;
    const int nt = r5 & 3;
    const int bm = mt * 64;
    const int bn = nt * 128;

    const float* Az = (const float*)args.A[z];
    const unsigned short* Wz = args.Wt[z];
    const float* biz = args.bias[z];
    unsigned short* Cz = (unsigned short*)args.C[z];

    const int tid = threadIdx.x;
    const int w   = tid >> 6;                    // wave 0..3
    const int l   = tid & 63;
    const int lr  = l & 15;
    const int lhi = l >> 4;
    const int wm  = (w >> 1) * 32;               // 2x2 wave grid, 32x64/wave
    const int wn  = (w & 1) * 64;

    f32x4 acc[2][4];
    #pragma unroll
    for (int m = 0; m < 2; ++m)
        #pragma unroll
        for (int n = 0; n < 4; ++n) acc[m][n] = (f32x4){0.f, 0.f, 0.f, 0.f};

    float4 fa[2][2];   // in-flight fp32 A tile: 4 float4 (16 VGPR)

    auto loadA_f32 = [&](int t) {                // 512 chunks: 2 / thread
        #pragma unroll
        for (int q = 0; q < 2; ++q) {
            const int cid = q * 256 + tid;
            const int r = cid >> 3;              // 0..63
            const int c = (cid & 7) ^ (r & 7);   // load-side XOR permutation
            const float* src = Az + (size_t)(bm + r) * D_ + t * 64 + c * 8;
            fa[q][0] = *(const float4*)src;
            fa[q][1] = *(const float4*)(src + 4);
        }
    };
    auto writeA_f32 = [&](int buf) {             // cvt_pk + 2 ds_write_b128
        #pragma unroll
        for (int q = 0; q < 2; ++q) {
            const int cid = q * 256 + tid;
            union { u32x4 u; u16x8 s; } cv;
            cv.u[0] = cvtpk(fa[q][0].x, fa[q][0].y);
            cv.u[1] = cvtpk(fa[q][0].z, fa[q][0].w);
            cv.u[2] = cvtpk(fa[q][1].x, fa[q][1].y);
            cv.u[3] = cvtpk(fa[q][1].z, fa[q][1].w);
            *(u16x8*)&As[buf][cid * 8] = cv.s;   // linear dest: conflict-free
        }
    };
    auto stageB = [&](int buf, int t) {          // 4 gload_lds / wave
        #pragma unroll
        for (int it = 0; it < 4; ++it) {
            const int cg  = it * 4 + w;
            const int cid = cg * 64 + l;
            const int r = cid >> 3;
            const int c = (cid & 7) ^ (r & 7);
            gload_lds16(Wz + (size_t)(bn + r) * D_ + t * 64 + c * 8,
                        &Bs[buf][cg * 512]);
        }
    };

    // Prologue: tile 0 staged, drained.
    loadA_f32(0);
    writeA_f32(0);
    stageB(0, 0);
    __syncthreads();

    for (int t = 0; t < 8; ++t) {                // K = 512 = 8 x 64
        if (t < 7) {
            loadA_f32(t + 1);                    // issue BEFORE compute
            stageB((t + 1) & 1, t + 1);
        }
        __builtin_amdgcn_s_setprio(1);
        #pragma unroll
        for (int kk = 0; kk < 2; ++kk) {
            bf16x8 af[2], bfr[4];
            #pragma unroll
            for (int fm = 0; fm < 2; ++fm) {
                const int row = wm + fm * 16 + lr;
                const int sl  = (kk * 4 + lhi) ^ (row & 7);
                af[fm] = *(const bf16x8*)&As[t & 1][row * 64 + sl * 8];
            }
            #pragma unroll
            for (int fn = 0; fn < 4; ++fn) {
                const int row = wn + fn * 16 + lr;
                const int sl  = (kk * 4 + lhi) ^ (row & 7);
                bfr[fn] = *(const bf16x8*)&Bs[t & 1][row * 64 + sl * 8];
            }
            #pragma unroll
            for (int fm = 0; fm < 2; ++fm)
                #pragma unroll
                for (int fn = 0; fn < 4; ++fn)
                    acc[fm][fn] = __builtin_amdgcn_mfma_f32_16x16x32_bf16(
                        af[fm], bfr[fn], acc[fm][fn], 0, 0, 0);
        }
        __builtin_amdgcn_s_setprio(0);
        if (t < 7) {
            writeA_f32((t + 1) & 1);   // readers of that buffer ended at t-1
            __syncthreads();           // single drain: B gloads + A ds_writes
        }
    }

    float bv[4];
    #pragma unroll
    for (int fn = 0; fn < 4; ++fn) bv[fn] = biz[bn + wn + fn * 16 + lr];

    #pragma unroll
    for (int fm = 0; fm < 2; ++fm)
        #pragma unroll
        for (int fn = 0; fn < 4; ++fn)
            #pragma unroll
            for (int rr = 0; rr < 4; ++rr) {
                const int row = bm + wm + fm * 16 + lhi * 4 + rr;
                const int col = bn + wn + fn * 16 + lr;
                Cz[(size_t)row * 512 + col] = f2bf(acc[fm][fn][rr] + bv[fn]);
            }
}

// ---------------------------------------------------------------------------
// Out-projection GEMM — r17-validated gemm_o64 (unchanged).
// ---------------------------------------------------------------------------
__global__ __launch_bounds__(256, 3)
void gemm_o64(const unsigned short* __restrict__ A,
              const unsigned short* __restrict__ W,
              const float* __restrict__ bias,
              float* __restrict__ C)
{
    __shared__ unsigned short As[2][64 * 64];    // 8 KB x2
    __shared__ unsigned short Bs[2][128 * 64];   // 16 KB x2

    const int id = blockIdx.x;                   // 512 blocks: 128 mt x 4 nt
    const int lg = (id & 7) * (gridDim.x >> 3) + (id >> 3);
    const int mt = lg >> 2;
    const int nt = lg & 3;
    const int bm = mt * 64;
    const int bn = nt * 128;

    const int tid = threadIdx.x;
    const int w   = tid >> 6;
    const int l   = tid & 63;
    const int lr  = l & 15;
    const int lhi = l >> 4;
    const int wm  = (w >> 1) * 32;
    const int wn  = (w & 1) * 64;

    f32x4 acc[2][4];
    #pragma unroll
    for (int m = 0; m < 2; ++m)
        #pragma unroll
        for (int n = 0; n < 4; ++n) acc[m][n] = (f32x4){0.f, 0.f, 0.f, 0.f};

    auto stage = [&](int buf, int t) {
        #pragma unroll
        for (int it = 0; it < 2; ++it) {
            const int cg  = it * 4 + w;
            const int cid = cg * 64 + l;
            const int r = cid >> 3;
            const int c = (cid & 7) ^ (r & 7);
            gload_lds16(A + (size_t)(bm + r) * D_ + t * 64 + c * 8,
                        &As[buf][cg * 512]);
        }
        #pragma unroll
        for (int it = 0; it < 4; ++it) {
            const int cg  = it * 4 + w;
            const int cid = cg * 64 + l;
            const int r = cid >> 3;
            const int c = (cid & 7) ^ (r & 7);
            gload_lds16(W + (size_t)(bn + r) * D_ + t * 64 + c * 8,
                        &Bs[buf][cg * 512]);
        }
    };

    stage(0, 0);
    __syncthreads();

    int buf = 0;
    for (int t = 0; t < 8; ++t) {
        if (t < 7) stage(buf ^ 1, t + 1);        // issue BEFORE compute
        __builtin_amdgcn_s_setprio(1);
        #pragma unroll
        for (int kk = 0; kk < 2; ++kk) {
            bf16x8 af[2], bfr[4];
            #pragma unroll
            for (int fm = 0; fm < 2; ++fm) {
                const int row = wm + fm * 16 + lr;
                const int sl  = (kk * 4 + lhi) ^ (row & 7);
                af[fm] = *(const bf16x8*)&As[buf][row * 64 + sl * 8];
            }
            #pragma unroll
            for (int fn = 0; fn < 4; ++fn) {
                const int row = wn + fn * 16 + lr;
                const int sl  = (kk * 4 + lhi) ^ (row & 7);
                bfr[fn] = *(const bf16x8*)&Bs[buf][row * 64 + sl * 8];
            }
            #pragma unroll
            for (int fm = 0; fm < 2; ++fm)
                #pragma unroll
                for (int fn = 0; fn < 4; ++fn)
                    acc[fm][fn] = __builtin_amdgcn_mfma_f32_16x16x32_bf16(
                        af[fm], bfr[fn], acc[fm][fn], 0, 0, 0);
        }
        __builtin_amdgcn_s_setprio(0);
        __syncthreads();
        buf ^= 1;
    }

    float bv[4];
    #pragma unroll
    for (int fn = 0; fn < 4; ++fn) bv[fn] = bias[bn + wn + fn * 16 + lr];

    #pragma unroll
    for (int fm = 0; fm < 2; ++fm)
        #pragma unroll
        for (int fn = 0; fn < 4; ++fn)
            #pragma unroll
            for (int rr = 0; rr < 4; ++rr) {
                const int row = bm + wm + fm * 16 + lhi * 4 + rr;
                const int col = bn + wn + fn * 16 + lr;
                C[(size_t)row * 512 + col] = acc[fm][fn][rr] + bv[fn];
            }
}

// ---------------------------------------------------------------------------
// MFMA banded-causal local attention (r17-validated: P unioned into Ksh,
// 49.2 KB -> 3 blocks/CU). Unchanged.
// ---------------------------------------------------------------------------
__global__ __launch_bounds__(256, 3)
void attn_mfma(const unsigned short* __restrict__ qb,
               const unsigned short* __restrict__ kb,
               const unsigned short* __restrict__ vb,
               unsigned short* __restrict__ ob)
{
    __shared__ unsigned short Ksh[192 * 64];      // 24 KB; becomes P after QK^T
    __shared__ unsigned short Vsh[4 * 192 * 16];  // 24 KB

    const int flat = blockIdx.x + 32 * (blockIdx.y + 8 * blockIdx.z);
    const int lg   = (flat & 7) * 128 + (flat >> 3);
    const int tile = lg & 31;
    const int h    = (lg >> 5) & 7;
    const int b    = lg >> 8;

    const int i0 = tile * 64;
    const int j0 = i0 - 128;
    const int tid = threadIdx.x;
    const int w   = tid >> 6;
    const int l   = tid & 63;
    const int lr  = l & 15;
    const int lhi = l >> 4;
    const float scale = 0.0220970869120796f;

    const size_t hbase = ((size_t)b * K_) * 512 + (size_t)h * 64;
    const unsigned short* kh = kb + hbase;
    const unsigned short* vh = vb + hbase;
    const unsigned short* qh = qb + hbase;
    unsigned short* oh = ob + hbase;

    #pragma unroll
    for (int it = 0; it < 6; ++it) {
        const int cg  = it * 4 + w;
        const int cid = cg * 64 + l;
        const int r = cid >> 3, c = cid & 7;
        const int cs = c ^ (r & 7);
        int j = j0 + r; if (j < 0) j = 0;
        gload_lds16(kh + (size_t)j * 512 + cs * 8, &Ksh[cg * 64 * 8]);
    }
    #pragma unroll
    for (int it = 0; it < 6; ++it) {
        const int cg  = it * 4 + w;
        const int cid = cg * 64 + l;
        const int blk = cid / 384;
        const int rem = cid - blk * 384;
        const int prow = rem >> 1, hf = rem & 1;
        const int a = prow >> 2, bb = prow & 3;
        const int k = (a < 24) ? (8 * a + bb) : (8 * (a - 24) + 4 + bb);
        int j = j0 + k; if (j < 0) j = 0;
        gload_lds16(vh + (size_t)j * 512 + blk * 16 + hf * 8, &Vsh[cg * 64 * 8]);
    }

    bf16x8 qa[2];
    {
        const unsigned short* qrow = qh + (size_t)(i0 + 16 * w + lr) * 512;
        qa[0] = *(const bf16x8*)(qrow + lhi * 8);
        qa[1] = *(const bf16x8*)(qrow + 32 + lhi * 8);
    }
    __syncthreads();

    const int jcbase = w & ~1;
    f32x4 sacc[10];
    #pragma unroll
    for (int jc = 0; jc < 10; ++jc) sacc[jc] = (f32x4){0.f, 0.f, 0.f, 0.f};

    __builtin_amdgcn_s_setprio(1);
    #pragma unroll
    for (int kk = 0; kk < 2; ++kk) {
        const int ch = (kk * 4 + lhi) ^ (lr & 7);
        #pragma unroll
        for (int jc = 0; jc < 10; ++jc) {
            const int row = (jcbase + jc) * 16 + lr;
            bf16x8 kf = *(const bf16x8*)&Ksh[row * 64 + ch * 8];
            sacc[jc] = __builtin_amdgcn_mfma_f32_16x16x32_bf16(
                qa[kk], kf, sacc[jc], 0, 0, 0);
        }
    }
    __builtin_amdgcn_s_setprio(0);

    __syncthreads();   // ALL waves done reading K -> Ksh reusable as P

    unsigned short* myP = &Ksh[w * 16 * 168];
    const int lo0 = 128 - i0;
    float lsum[4] = {0.f, 0.f, 0.f, 0.f};
    #pragma unroll
    for (int jc = 0; jc < 10; ++jc) {
        const int jcol = (jcbase + jc) * 16 + lr;
        #pragma unroll
        for (int rr = 0; rr < 4; ++rr) {
            const int iloc = 16 * w + 4 * lhi + rr;
            const bool ok = (jcol >= iloc) && (jcol <= iloc + ATTN_) && (jcol >= lo0);
            const float p = ok ? __expf(fminf(sacc[jc][rr] * scale, 80.f)) : 0.f;
            lsum[rr] += p;
            myP[(4 * lhi + rr) * 168 + jc * 16 + lr] = f2bf(p);
        }
    }
    #pragma unroll
    for (int rr = 0; rr < 4; ++rr) {
        float s = lsum[rr];
        s += __shfl_xor(s, 1, 16);
        s += __shfl_xor(s, 2, 16);
        s += __shfl_xor(s, 4, 16);
        s += __shfl_xor(s, 8, 16);
        lsum[rr] = s;
    }

    const int kcbase = w >> 1;
    f32x4 oacc[4];
    #pragma unroll
    for (int fn = 0; fn < 4; ++fn) oacc[fn] = (f32x4){0.f, 0.f, 0.f, 0.f};
    const unsigned vbase = lds_addr(&Vsh[0]) + (unsigned)(l * 8);

    for (int kc5 = 0; kc5 < 5; ++kc5) {
        const int kc = kcbase + kc5;
        bf16x8 pa = *(const bf16x8*)&myP[lr * 168 + kc5 * 32 + lhi * 8];
        u32x2 vlo[4], vhi[4];
        #pragma unroll
        for (int fn = 0; fn < 4; ++fn) {
            const unsigned addr = vbase + (unsigned)((fn * 3072 + kc * 256) * 2);
            asm volatile("ds_read_b64_tr_b16 %0, %1" : "=v"(vlo[fn]) : "v"(addr));
            asm volatile("ds_read_b64_tr_b16 %0, %1 offset:3072"
                         : "=v"(vhi[fn]) : "v"(addr));
        }
        asm volatile("s_waitcnt lgkmcnt(0)" ::: "memory");
        __builtin_amdgcn_sched_barrier(0);
        __builtin_amdgcn_s_setprio(1);
        #pragma unroll
        for (int fn = 0; fn < 4; ++fn) {
            union { u32x2 h[2]; bf16x8 v; } u;
            u.h[0] = vlo[fn]; u.h[1] = vhi[fn];
            oacc[fn] = __builtin_amdgcn_mfma_f32_16x16x32_bf16(
                pa, u.v, oacc[fn], 0, 0, 0);
        }
        __builtin_amdgcn_s_setprio(0);
    }

    float inv[4];
    #pragma unroll
    for (int rr = 0; rr < 4; ++rr) inv[rr] = 1.f / lsum[rr];
    #pragma unroll
    for (int fn = 0; fn < 4; ++fn)
        #pragma unroll
        for (int rr = 0; rr < 4; ++rr) {
            const int row = i0 + 16 * w + 4 * lhi + rr;
            oh[(size_t)row * 512 + fn * 16 + lr] = f2bf(oacc[fn][rr] * inv[rr]);
        }
}

// ---------------------------------------------------------------------------
extern "C" void kernel_launch(void* const* d_in, const int* in_sizes, int n_in,
                              void* d_out, int out_size, void* d_ws, size_t ws_size,
                              hipStream_t stream)
{
    const float* query = (const float*)d_in[0];
    const float* key   = (const float*)d_in[1];
    const float* value = (const float*)d_in[2];
    const float* W_q   = (const float*)d_in[3];
    const float* b_q   = (const float*)d_in[4];
    const float* W_k   = (const float*)d_in[5];
    const float* b_k   = (const float*)d_in[6];
    const float* W_v   = (const float*)d_in[7];
    const float* b_v   = (const float*)d_in[8];
    const float* W_o   = (const float*)d_in[9];
    const float* b_o   = (const float*)d_in[10];
    float* out = (float*)d_out;

    const size_t NX = (size_t)M_ * 512;
    const size_t NW = 512 * 512;
    unsigned short* wqb = (unsigned short*)d_ws;
    unsigned short* wkb = wqb + NW;
    unsigned short* wvb = wkb + NW;
    unsigned short* wob = wvb + NW;
    unsigned short* qp  = wob + NW;
    unsigned short* kp  = qp + NX;
    unsigned short* vp  = kp + NX;
    unsigned short* ap  = vp + NX;

    const int NW8 = (int)(NW / 8);

    CvtA a;
    a.c[0] = { W_q, wqb, NW8 };
    a.c[1] = { W_k, wkb, NW8 };
    a.c[2] = { W_v, wvb, NW8 };
    a.c[3] = { W_o, wob, NW8 };
    cvt_multi<<<dim3(32, 4), 256, 0, stream>>>(a);

    GArgs qa;
    qa.A[0] = query; qa.A[1] = key; qa.A[2] = value;
    qa.Wt[0] = wqb;  qa.Wt[1] = wkb; qa.Wt[2] = wvb;
    qa.bias[0] = b_q; qa.bias[1] = b_k; qa.bias[2] = b_v;
    qa.C[0] = qp; qa.C[1] = kp; qa.C[2] = vp;
    gemm_qkv64<<<1536, 256, 0, stream>>>(qa);    // 3z x 128mt x 4nt

    attn_mfma<<<dim3(32, 8, 4), 256, 0, stream>>>(qp, kp, vp, ap);

    gemm_o64<<<512, 256, 0, stream>>>(ap, wob, b_o, out);  // 128 mt x 4 nt
}

// Round 20
// 53.984 us; speedup vs baseline: 1.3202x; 1.0515x over previous
//
#include <hip/hip_runtime.h>
#include <hip/hip_bf16.h>
#include <stdint.h>

#define B_ 4
#define K_ 2048
#define D_ 512
#define H_ 8
#define ATTN_ 128
#define M_ (B_ * K_)   // 8192

typedef __attribute__((ext_vector_type(4))) float f32x4;
typedef __attribute__((ext_vector_type(8))) short bf16x8;
typedef __attribute__((ext_vector_type(8))) unsigned short u16x8;
typedef __attribute__((ext_vector_type(2))) unsigned int u32x2;
typedef __attribute__((ext_vector_type(4))) unsigned int u32x4;

__device__ __forceinline__ unsigned short f2bf(float f) {
    union { float f; unsigned int i; } x; x.f = f;
    unsigned int r = x.i + 0x7fffu + ((x.i >> 16) & 1u);   // RNE
    return (unsigned short)(r >> 16);
}
__device__ __forceinline__ float bf2f(unsigned short u) {
    union { unsigned int i; float f; } x; x.i = ((unsigned int)u) << 16; return x.f;
}
__device__ __forceinline__ unsigned cvtpk(float lo, float hi) {   // r11/r16-validated
    unsigned r;
    asm("v_cvt_pk_bf16_f32 %0, %1, %2" : "=v"(r) : "v"(lo), "v"(hi));
    return r;
}
__device__ __forceinline__ void gload_lds16(const unsigned short* g, unsigned short* l) {
    __builtin_amdgcn_global_load_lds(
        (const __attribute__((address_space(1))) void*)g,
        (__attribute__((address_space(3))) void*)l, 16, 0, 0);
}
__device__ __forceinline__ unsigned lds_addr(const void* p) {
    return (unsigned)(unsigned long long)
        (const __attribute__((address_space(3))) void*)p;
}

// ---------------------------------------------------------------------------
// fp32 -> bf16 conversion: weights only (4 tensors)
// ---------------------------------------------------------------------------
struct Cvt { const float* s; unsigned short* d; int n8; };
struct CvtA { Cvt c[4]; };

__global__ __launch_bounds__(256)
void cvt_multi(CvtA a) {
    const Cvt c = a.c[blockIdx.y];
    const float4* s4 = (const float4*)c.s;
    u16x8* d8 = (u16x8*)c.d;
    for (int g = blockIdx.x * 256 + threadIdx.x; g < c.n8; g += gridDim.x * 256) {
        float4 f0 = s4[2 * g], f1 = s4[2 * g + 1];
        u16x8 o;
        o[0] = f2bf(f0.x); o[1] = f2bf(f0.y); o[2] = f2bf(f0.z); o[3] = f2bf(f0.w);
        o[4] = f2bf(f1.x); o[5] = f2bf(f1.y); o[6] = f2bf(f1.z); o[7] = f2bf(f1.w);
        d8[g] = o;
    }
}

// ---------------------------------------------------------------------------
// QKV GEMM — r14/r16/r17 structure (best measured).
//   128x128 tile, BK=64, 256 thr (4 waves 2x2), As single 16 KB + Bs[2]
//   32 KB = 48 KB -> 3 blocks/CU. Loads for t+1 issued BEFORE compute(t).
// ---------------------------------------------------------------------------
struct GArgs {
    const void* A[3];
    const unsigned short* Wt[3];
    const float* bias[3];
    void* C[3];
};

__global__ __launch_bounds__(256, 3)
void gemm_qkv128(GArgs args)
{
    __shared__ unsigned short As[128 * 64];      // 16 KB (single)
    __shared__ unsigned short Bs[2][128 * 64];   // 32 KB (double)

    const int id = blockIdx.x;
    const int lg = (id & 7) * (gridDim.x >> 3) + (id >> 3);  // XCD-contiguous
    const int g  = lg >> 2;                      // m-group (shares A-tile)
    const int nt = lg & 3;
    const int z  = g >> 6;
    const int mt = g & 63;
    const int bm = mt * 128;
    const int bn = nt * 128;

    const float* Az = (const float*)args.A[z];
    const unsigned short* Wz = args.Wt[z];
    const float* biz = args.bias[z];
    unsigned short* Cz = (unsigned short*)args.C[z];

    const int tid = threadIdx.x;
    const int w   = tid >> 6;                    // wave 0..3
    const int l   = tid & 63;
    const int lr  = l & 15;
    const int lhi = l >> 4;
    const int wm  = (w >> 1) * 64;               // 2x2 wave grid
    const int wn  = (w & 1) * 64;

    f32x4 acc[4][4];
    #pragma unroll
    for (int m = 0; m < 4; ++m)
        #pragma unroll
        for (int n = 0; n < 4; ++n) acc[m][n] = (f32x4){0.f, 0.f, 0.f, 0.f};

    float4 fa[4][2];   // in-flight fp32 A tile (32 VGPR)

    auto loadA_f32 = [&](int t) {                // 8 float4 / thread
        #pragma unroll
        for (int q = 0; q < 4; ++q) {
            const int cid = q * 256 + tid;       // 1024 chunks: 128 rows x 8
            const int r = cid >> 3;
            const int c = (cid & 7) ^ (r & 7);   // load-side XOR permutation
            const float* src = Az + (size_t)(bm + r) * D_ + t * 64 + c * 8;
            fa[q][0] = *(const float4*)src;
            fa[q][1] = *(const float4*)(src + 4);
        }
    };
    auto writeA_f32 = [&]() {                    // cvt_pk + 4 ds_write_b128
        #pragma unroll
        for (int q = 0; q < 4; ++q) {
            const int cid = q * 256 + tid;
            union { u32x4 u; u16x8 s; } cv;
            cv.u[0] = cvtpk(fa[q][0].x, fa[q][0].y);
            cv.u[1] = cvtpk(fa[q][0].z, fa[q][0].w);
            cv.u[2] = cvtpk(fa[q][1].x, fa[q][1].y);
            cv.u[3] = cvtpk(fa[q][1].z, fa[q][1].w);
            *(u16x8*)&As[cid * 8] = cv.s;        // linear dest: conflict-free
        }
    };
    auto stageB = [&](int buf, int t) {          // 4 gload_lds / wave
        #pragma unroll
        for (int it = 0; it < 4; ++it) {
            const int cg  = it * 4 + w;
            const int cid = cg * 64 + l;
            const int r = cid >> 3;
            const int c = (cid & 7) ^ (r & 7);
            gload_lds16(Wz + (size_t)(bn + r) * D_ + t * 64 + c * 8,
                        &Bs[buf][cg * 512]);
        }
    };

    loadA_f32(0);
    writeA_f32();
    stageB(0, 0);
    __syncthreads();

    for (int t = 0; t < 8; ++t) {                // K = 512 = 8 x 64
        if (t < 7) {
            loadA_f32(t + 1);                    // global->reg (flies)
            stageB((t + 1) & 1, t + 1);          // gload_lds -> other buffer
        }
        __builtin_amdgcn_s_setprio(1);
        #pragma unroll
        for (int kk = 0; kk < 2; ++kk) {
            bf16x8 af[4], bfr[4];
            #pragma unroll
            for (int fm = 0; fm < 4; ++fm) {
                const int row = wm + fm * 16 + lr;
                const int sl  = (kk * 4 + lhi) ^ (row & 7);
                af[fm] = *(const bf16x8*)&As[row * 64 + sl * 8];
            }
            #pragma unroll
            for (int fn = 0; fn < 4; ++fn) {
                const int row = wn + fn * 16 + lr;
                const int sl  = (kk * 4 + lhi) ^ (row & 7);
                bfr[fn] = *(const bf16x8*)&Bs[t & 1][row * 64 + sl * 8];
            }
            #pragma unroll
            for (int fm = 0; fm < 4; ++fm)
                #pragma unroll
                for (int fn = 0; fn < 4; ++fn)
                    acc[fm][fn] = __builtin_amdgcn_mfma_f32_16x16x32_bf16(
                        af[fm], bfr[fn], acc[fm][fn], 0, 0, 0);
        }
        __builtin_amdgcn_s_setprio(0);
        if (t < 7) {
            __syncthreads();     // As read-drain + vmcnt (loads long landed)
            writeA_f32();        // tile t+1's A -> As (cvt + ds_write)
            __syncthreads();     // lgkm drain: As visible for next step
        }
    }

    float bv[4];
    #pragma unroll
    for (int fn = 0; fn < 4; ++fn) bv[fn] = biz[bn + wn + fn * 16 + lr];

    #pragma unroll
    for (int fm = 0; fm < 4; ++fm)
        #pragma unroll
        for (int fn = 0; fn < 4; ++fn)
            #pragma unroll
            for (int rr = 0; rr < 4; ++rr) {
                const int row = bm + wm + fm * 16 + lhi * 4 + rr;
                const int col = bn + wn + fn * 16 + lr;
                Cz[(size_t)row * 512 + col] = f2bf(acc[fm][fn][rr] + bv[fn]);
            }
}

// ---------------------------------------------------------------------------
// Out-projection GEMM — 64x128 tile (r17-validated, ~614 TF).
// 512 blocks x 48 KB -> all co-resident in one batch.
// ---------------------------------------------------------------------------
__global__ __launch_bounds__(256, 3)
void gemm_o64(const unsigned short* __restrict__ A,
              const unsigned short* __restrict__ W,
              const float* __restrict__ bias,
              float* __restrict__ C)
{
    __shared__ unsigned short As[2][64 * 64];    // 8 KB x2
    __shared__ unsigned short Bs[2][128 * 64];   // 16 KB x2

    const int id = blockIdx.x;                   // 512 blocks: 128 mt x 4 nt
    const int lg = (id & 7) * (gridDim.x >> 3) + (id >> 3);  // XCD-contiguous
    const int mt = lg >> 2;
    const int nt = lg & 3;
    const int bm = mt * 64;
    const int bn = nt * 128;

    const int tid = threadIdx.x;
    const int w   = tid >> 6;                    // wave 0..3
    const int l   = tid & 63;
    const int lr  = l & 15;
    const int lhi = l >> 4;
    const int wm  = (w >> 1) * 32;               // 2x2 wave grid, tile 32x64
    const int wn  = (w & 1) * 64;

    f32x4 acc[2][4];
    #pragma unroll
    for (int m = 0; m < 2; ++m)
        #pragma unroll
        for (int n = 0; n < 4; ++n) acc[m][n] = (f32x4){0.f, 0.f, 0.f, 0.f};

    auto stage = [&](int buf, int t) {
        #pragma unroll
        for (int it = 0; it < 2; ++it) {
            const int cg  = it * 4 + w;
            const int cid = cg * 64 + l;
            const int r = cid >> 3;
            const int c = (cid & 7) ^ (r & 7);
            gload_lds16(A + (size_t)(bm + r) * D_ + t * 64 + c * 8,
                        &As[buf][cg * 512]);
        }
        #pragma unroll
        for (int it = 0; it < 4; ++it) {
            const int cg  = it * 4 + w;
            const int cid = cg * 64 + l;
            const int r = cid >> 3;
            const int c = (cid & 7) ^ (r & 7);
            gload_lds16(W + (size_t)(bn + r) * D_ + t * 64 + c * 8,
                        &Bs[buf][cg * 512]);
        }
    };

    stage(0, 0);
    __syncthreads();

    int buf = 0;
    for (int t = 0; t < 8; ++t) {
        if (t < 7) stage(buf ^ 1, t + 1);        // issue BEFORE compute
        __builtin_amdgcn_s_setprio(1);
        #pragma unroll
        for (int kk = 0; kk < 2; ++kk) {
            bf16x8 af[2], bfr[4];
            #pragma unroll
            for (int fm = 0; fm < 2; ++fm) {
                const int row = wm + fm * 16 + lr;
                const int sl  = (kk * 4 + lhi) ^ (row & 7);
                af[fm] = *(const bf16x8*)&As[buf][row * 64 + sl * 8];
            }
            #pragma unroll
            for (int fn = 0; fn < 4; ++fn) {
                const int row = wn + fn * 16 + lr;
                const int sl  = (kk * 4 + lhi) ^ (row & 7);
                bfr[fn] = *(const bf16x8*)&Bs[buf][row * 64 + sl * 8];
            }
            #pragma unroll
            for (int fm = 0; fm < 2; ++fm)
                #pragma unroll
                for (int fn = 0; fn < 4; ++fn)
                    acc[fm][fn] = __builtin_amdgcn_mfma_f32_16x16x32_bf16(
                        af[fm], bfr[fn], acc[fm][fn], 0, 0, 0);
        }
        __builtin_amdgcn_s_setprio(0);
        __syncthreads();                         // loads had full compute to land
        buf ^= 1;
    }

    float bv[4];
    #pragma unroll
    for (int fn = 0; fn < 4; ++fn) bv[fn] = bias[bn + wn + fn * 16 + lr];

    #pragma unroll
    for (int fm = 0; fm < 2; ++fm)
        #pragma unroll
        for (int fn = 0; fn < 4; ++fn)
            #pragma unroll
            for (int rr = 0; rr < 4; ++rr) {
                const int row = bm + wm + fm * 16 + lhi * 4 + rr;
                const int col = bn + wn + fn * 16 + lr;
                C[(size_t)row * 512 + col] = acc[fm][fn][rr] + bv[fn];
            }
}

// ---------------------------------------------------------------------------
// MFMA banded-causal local attention (r17-validated: P unioned into Ksh,
// 49.2 KB -> 3 blocks/CU).
// ---------------------------------------------------------------------------
__global__ __launch_bounds__(256, 3)
void attn_mfma(const unsigned short* __restrict__ qb,
               const unsigned short* __restrict__ kb,
               const unsigned short* __restrict__ vb,
               unsigned short* __restrict__ ob)
{
    __shared__ unsigned short Ksh[192 * 64];      // 24 KB; becomes P after QK^T
    __shared__ unsigned short Vsh[4 * 192 * 16];  // 24 KB

    const int flat = blockIdx.x + 32 * (blockIdx.y + 8 * blockIdx.z);
    const int lg   = (flat & 7) * 128 + (flat >> 3);
    const int tile = lg & 31;
    const int h    = (lg >> 5) & 7;
    const int b    = lg >> 8;

    const int i0 = tile * 64;
    const int j0 = i0 - 128;
    const int tid = threadIdx.x;
    const int w   = tid >> 6;
    const int l   = tid & 63;
    const int lr  = l & 15;
    const int lhi = l >> 4;
    const float scale = 0.0220970869120796f;

    const size_t hbase = ((size_t)b * K_) * 512 + (size_t)h * 64;
    const unsigned short* kh = kb + hbase;
    const unsigned short* vh = vb + hbase;
    const unsigned short* qh = qb + hbase;
    unsigned short* oh = ob + hbase;

    #pragma unroll
    for (int it = 0; it < 6; ++it) {
        const int cg  = it * 4 + w;
        const int cid = cg * 64 + l;
        const int r = cid >> 3, c = cid & 7;
        const int cs = c ^ (r & 7);
        int j = j0 + r; if (j < 0) j = 0;
        gload_lds16(kh + (size_t)j * 512 + cs * 8, &Ksh[cg * 64 * 8]);
    }
    #pragma unroll
    for (int it = 0; it < 6; ++it) {
        const int cg  = it * 4 + w;
        const int cid = cg * 64 + l;
        const int blk = cid / 384;
        const int rem = cid - blk * 384;
        const int prow = rem >> 1, hf = rem & 1;
        const int a = prow >> 2, bb = prow & 3;
        const int k = (a < 24) ? (8 * a + bb) : (8 * (a - 24) + 4 + bb);
        int j = j0 + k; if (j < 0) j = 0;
        gload_lds16(vh + (size_t)j * 512 + blk * 16 + hf * 8, &Vsh[cg * 64 * 8]);
    }

    bf16x8 qa[2];
    {
        const unsigned short* qrow = qh + (size_t)(i0 + 16 * w + lr) * 512;
        qa[0] = *(const bf16x8*)(qrow + lhi * 8);
        qa[1] = *(const bf16x8*)(qrow + 32 + lhi * 8);
    }
    __syncthreads();

    const int jcbase = w & ~1;
    f32x4 sacc[10];
    #pragma unroll
    for (int jc = 0; jc < 10; ++jc) sacc[jc] = (f32x4){0.f, 0.f, 0.f, 0.f};

    __builtin_amdgcn_s_setprio(1);
    #pragma unroll
    for (int kk = 0; kk < 2; ++kk) {
        const int ch = (kk * 4 + lhi) ^ (lr & 7);
        #pragma unroll
        for (int jc = 0; jc < 10; ++jc) {
            const int row = (jcbase + jc) * 16 + lr;
            bf16x8 kf = *(const bf16x8*)&Ksh[row * 64 + ch * 8];
            sacc[jc] = __builtin_amdgcn_mfma_f32_16x16x32_bf16(
                qa[kk], kf, sacc[jc], 0, 0, 0);
        }
    }
    __builtin_amdgcn_s_setprio(0);

    __syncthreads();   // ALL waves done reading K -> Ksh reusable as P

    unsigned short* myP = &Ksh[w * 16 * 168];
    const int lo0 = 128 - i0;
    float lsum[4] = {0.f, 0.f, 0.f, 0.f};
    #pragma unroll
    for (int jc = 0; jc < 10; ++jc) {
        const int jcol = (jcbase + jc) * 16 + lr;
        #pragma unroll
        for (int rr = 0; rr < 4; ++rr) {
            const int iloc = 16 * w + 4 * lhi + rr;
            const bool ok = (jcol >= iloc) && (jcol <= iloc + ATTN_) && (jcol >= lo0);
            const float p = ok ? __expf(fminf(sacc[jc][rr] * scale, 80.f)) : 0.f;
            lsum[rr] += p;
            myP[(4 * lhi + rr) * 168 + jc * 16 + lr] = f2bf(p);
        }
    }
    #pragma unroll
    for (int rr = 0; rr < 4; ++rr) {
        float s = lsum[rr];
        s += __shfl_xor(s, 1, 16);
        s += __shfl_xor(s, 2, 16);
        s += __shfl_xor(s, 4, 16);
        s += __shfl_xor(s, 8, 16);
        lsum[rr] = s;
    }

    const int kcbase = w >> 1;
    f32x4 oacc[4];
    #pragma unroll
    for (int fn = 0; fn < 4; ++fn) oacc[fn] = (f32x4){0.f, 0.f, 0.f, 0.f};
    const unsigned vbase = lds_addr(&Vsh[0]) + (unsigned)(l * 8);

    for (int kc5 = 0; kc5 < 5; ++kc5) {
        const int kc = kcbase + kc5;
        bf16x8 pa = *(const bf16x8*)&myP[lr * 168 + kc5 * 32 + lhi * 8];
        u32x2 vlo[4], vhi[4];
        #pragma unroll
        for (int fn = 0; fn < 4; ++fn) {
            const unsigned addr = vbase + (unsigned)((fn * 3072 + kc * 256) * 2);
            asm volatile("ds_read_b64_tr_b16 %0, %1" : "=v"(vlo[fn]) : "v"(addr));
            asm volatile("ds_read_b64_tr_b16 %0, %1 offset:3072"
                         : "=v"(vhi[fn]) : "v"(addr));
        }
        asm volatile("s_waitcnt lgkmcnt(0)" ::: "memory");
        __builtin_amdgcn_sched_barrier(0);
        __builtin_amdgcn_s_setprio(1);
        #pragma unroll
        for (int fn = 0; fn < 4; ++fn) {
            union { u32x2 h[2]; bf16x8 v; } u;
            u.h[0] = vlo[fn]; u.h[1] = vhi[fn];
            oacc[fn] = __builtin_amdgcn_mfma_f32_16x16x32_bf16(
                pa, u.v, oacc[fn], 0, 0, 0);
        }
        __builtin_amdgcn_s_setprio(0);
    }

    float inv[4];
    #pragma unroll
    for (int rr = 0; rr < 4; ++rr) inv[rr] = 1.f / lsum[rr];
    #pragma unroll
    for (int fn = 0; fn < 4; ++fn)
        #pragma unroll
        for (int rr = 0; rr < 4; ++rr) {
            const int row = i0 + 16 * w + 4 * lhi + rr;
            oh[(size_t)row * 512 + fn * 16 + lr] = f2bf(oacc[fn][rr] * inv[rr]);
        }
}

// ---------------------------------------------------------------------------
extern "C" void kernel_launch(void* const* d_in, const int* in_sizes, int n_in,
                              void* d_out, int out_size, void* d_ws, size_t ws_size,
                              hipStream_t stream)
{
    const float* query = (const float*)d_in[0];
    const float* key   = (const float*)d_in[1];
    const float* value = (const float*)d_in[2];
    const float* W_q   = (const float*)d_in[3];
    const float* b_q   = (const float*)d_in[4];
    const float* W_k   = (const float*)d_in[5];
    const float* b_k   = (const float*)d_in[6];
    const float* W_v   = (const float*)d_in[7];
    const float* b_v   = (const float*)d_in[8];
    const float* W_o   = (const float*)d_in[9];
    const float* b_o   = (const float*)d_in[10];
    float* out = (float*)d_out;

    const size_t NX = (size_t)M_ * 512;
    const size_t NW = 512 * 512;
    unsigned short* wqb = (unsigned short*)d_ws;
    unsigned short* wkb = wqb + NW;
    unsigned short* wvb = wkb + NW;
    unsigned short* wob = wvb + NW;
    unsigned short* qp  = wob + NW;
    unsigned short* kp  = qp + NX;
    unsigned short* vp  = kp + NX;
    unsigned short* ap  = vp + NX;

    const int NW8 = (int)(NW / 8);

    CvtA a;
    a.c[0] = { W_q, wqb, NW8 };
    a.c[1] = { W_k, wkb, NW8 };
    a.c[2] = { W_v, wvb, NW8 };
    a.c[3] = { W_o, wob, NW8 };
    cvt_multi<<<dim3(32, 4), 256, 0, stream>>>(a);

    GArgs qa;
    qa.A[0] = query; qa.A[1] = key; qa.A[2] = value;
    qa.Wt[0] = wqb;  qa.Wt[1] = wkb; qa.Wt[2] = wvb;
    qa.bias[0] = b_q; qa.bias[1] = b_k; qa.bias[2] = b_v;
    qa.C[0] = qp; qa.C[1] = kp; qa.C[2] = vp;
    gemm_qkv128<<<768, 256, 0, stream>>>(qa);    // 192 m-groups x 4 nt

    attn_mfma<<<dim3(32, 8, 4), 256, 0, stream>>>(qp, kp, vp, ap);

    gemm_o64<<<512, 256, 0, stream>>>(ap, wob, b_o, out);  // 128 mt x 4 nt
}